// Round 1
// baseline (7109.008 us; speedup 1.0000x reference)
//
#include <hip/hip_runtime.h>
#include <math.h>

#define CC 128
#define HH 64
#define RBD 8

__device__ __forceinline__ float silu_f(float x) {
    return x / (1.0f + __expf(-x));
}

// ---------------- zero scratch ----------------
__global__ void k_zero(float* __restrict__ p, int n) {
    int i = blockIdx.x * blockDim.x + threadIdx.x;
    int stride = gridDim.x * blockDim.x;
    for (; i < n; i += stride) p[i] = 0.0f;
}

// ---------------- transpose MLP weights ----------------
// w0 (8x64)->w0T(64x8), w1/w2 (64x64)->T, w3 (64x512)->w3T(512x64)
__global__ void k_prep(const float* __restrict__ w0, const float* __restrict__ w1,
                       const float* __restrict__ w2, const float* __restrict__ w3,
                       float* __restrict__ w0T, float* __restrict__ w1T,
                       float* __restrict__ w2T, float* __restrict__ w3T) {
    int i = blockIdx.x * blockDim.x + threadIdx.x;
    if (i < 64 * 8) { int m = i / 8, k = i % 8; w0T[i] = w0[k * 64 + m]; }
    if (i < 64 * 64) { int m = i / 64, k = i % 64; w1T[i] = w1[k * 64 + m]; w2T[i] = w2[k * 64 + m]; }
    if (i < 512 * 64) { int j = i / 64, k = i % 64; w3T[i] = w3[k * 512 + j]; }
}

// ---------------- node linear: y0 = xs@W1_0*inv_c, y1 = xv@W1_1*inv_c ----------------
__global__ __launch_bounds__(128) void k_node_lin(
    const float* __restrict__ xs, const float* __restrict__ xv,
    const float* __restrict__ W10, const float* __restrict__ W11,
    float* __restrict__ y0, float* __restrict__ y1, int N) {
    const int d = threadIdx.x;
    const int n0 = blockIdx.x * 4;
    const float inv_c = 0.08838834764831845f; // 1/sqrt(128)
    float a0[4] = {0.f, 0.f, 0.f, 0.f};
    float av[4][3] = {};
    #pragma unroll 4
    for (int c = 0; c < CC; c++) {
        float w10 = W10[c * CC + d];
        float w11 = W11[c * CC + d];
        #pragma unroll
        for (int n = 0; n < 4; n++) {
            a0[n] += xs[(n0 + n) * CC + c] * w10;
            #pragma unroll
            for (int i = 0; i < 3; i++)
                av[n][i] += xv[((n0 + n) * CC + c) * 3 + i] * w11;
        }
    }
    #pragma unroll
    for (int n = 0; n < 4; n++) {
        y0[(n0 + n) * CC + d] = a0[n] * inv_c;
        #pragma unroll
        for (int i = 0; i < 3; i++)
            y1[((n0 + n) * CC + d) * 3 + i] = av[n][i] * inv_c;
    }
}

// ---------------- fused edge kernel ----------------
// lane = edge. Full radial MLP in registers (fully unrolled, static indexing),
// then per-output-column dot with w3T + tensor product + atomic scatter.
__global__ __launch_bounds__(256, 2) void k_edge(
    const float* __restrict__ rb, const float* __restrict__ evec,
    const int* __restrict__ snd, const int* __restrict__ rcv,
    const float* __restrict__ y0, const float* __restrict__ y1,
    const float* __restrict__ w0T, const float* __restrict__ w1T,
    const float* __restrict__ w2T, const float* __restrict__ w3T,
    float* __restrict__ agg_s, float* __restrict__ agg_v, int E_) {
    int e = blockIdx.x * blockDim.x + threadIdx.x;
    if (e >= E_) return;

    float rbv[RBD];
    #pragma unroll
    for (int k = 0; k < RBD; k++) rbv[k] = rb[e * RBD + k];

    float ha[HH], hb[HH];
    // h0 = silu(rb @ w0)
    #pragma unroll
    for (int m = 0; m < HH; m++) {
        float a = 0.f;
        #pragma unroll
        for (int k = 0; k < RBD; k++) a += rbv[k] * w0T[m * RBD + k];
        ha[m] = silu_f(a);
    }
    // h1 = silu(h0 @ w1)
    #pragma unroll
    for (int m = 0; m < HH; m++) {
        float a = 0.f;
        #pragma unroll
        for (int k = 0; k < HH; k++) a += ha[k] * w1T[m * HH + k];
        hb[m] = silu_f(a);
    }
    // h2 = silu(h1 @ w2)
    #pragma unroll
    for (int m = 0; m < HH; m++) {
        float a = 0.f;
        #pragma unroll
        for (int k = 0; k < HH; k++) a += hb[k] * w2T[m * HH + k];
        ha[m] = silu_f(a);
    }
    // ha now holds final hidden h2 (64)

    int s = snd[e], r = rcv[e];
    float e0 = evec[e * 3 + 0], e1 = evec[e * 3 + 1], e2 = evec[e * 3 + 2];
    float rn = sqrtf(e0 * e0 + e1 * e1 + e2 * e2);
    float inv = 1.0f / fmaxf(rn, 1e-12f);
    float ux = e0 * inv, uy = e1 * inv, uz = e2 * inv;
    const float SQ3 = 1.7320508075688772f;
    float Yx = SQ3 * ux, Yy = SQ3 * uy, Yz = SQ3 * uz;

    const float* y0r = y0 + (size_t)s * CC;
    const float* y1r = y1 + (size_t)s * CC * 3;
    float* asr = agg_s + (size_t)r * (2 * CC);
    float* avr = agg_v + (size_t)r * (2 * CC * 3);

    // part 0: agg_s[r][c] += m0[c] * w[c]
    for (int c = 0; c < CC; c += 4) {
        float4 m0 = *(const float4*)(y0r + c);
        float m0a[4] = {m0.x, m0.y, m0.z, m0.w};
        #pragma unroll
        for (int q = 0; q < 4; q++) {
            float a = 0.f;
            #pragma unroll
            for (int k = 0; k < HH; k++) a += ha[k] * w3T[(0 * CC + c + q) * HH + k];
            atomicAdd(asr + c + q, m0a[q] * a);
        }
    }
    // part 1: agg_s[r][C+c] += (m1[c] . u) * w[C+c]
    for (int c = 0; c < CC; c += 4) {
        float4 va = *(const float4*)(y1r + c * 3);
        float4 vb = *(const float4*)(y1r + c * 3 + 4);
        float4 vc = *(const float4*)(y1r + c * 3 + 8);
        float t0[4];
        t0[0] = va.x * ux + va.y * uy + va.z * uz;
        t0[1] = va.w * ux + vb.x * uy + vb.y * uz;
        t0[2] = vb.z * ux + vb.w * uy + vc.x * uz;
        t0[3] = vc.y * ux + vc.z * uy + vc.w * uz;
        #pragma unroll
        for (int q = 0; q < 4; q++) {
            float a = 0.f;
            #pragma unroll
            for (int k = 0; k < HH; k++) a += ha[k] * w3T[(1 * CC + c + q) * HH + k];
            atomicAdd(asr + CC + c + q, t0[q] * a);
        }
    }
    // part 2: agg_v[r][c][i] += m0[c]*Y1[i]*w[2C+c]
    for (int c = 0; c < CC; c += 4) {
        float4 m0 = *(const float4*)(y0r + c);
        float m0a[4] = {m0.x, m0.y, m0.z, m0.w};
        #pragma unroll
        for (int q = 0; q < 4; q++) {
            float a = 0.f;
            #pragma unroll
            for (int k = 0; k < HH; k++) a += ha[k] * w3T[(2 * CC + c + q) * HH + k];
            float base = m0a[q] * a;
            atomicAdd(avr + (c + q) * 3 + 0, base * Yx);
            atomicAdd(avr + (c + q) * 3 + 1, base * Yy);
            atomicAdd(avr + (c + q) * 3 + 2, base * Yz);
        }
    }
    // part 3: agg_v[r][C+c][i] += m1[c][i]*w[3C+c]
    for (int c = 0; c < CC; c += 4) {
        float4 va = *(const float4*)(y1r + c * 3);
        float4 vb = *(const float4*)(y1r + c * 3 + 4);
        float4 vc = *(const float4*)(y1r + c * 3 + 8);
        float m1v[4][3] = {{va.x, va.y, va.z}, {va.w, vb.x, vb.y},
                           {vb.z, vb.w, vc.x}, {vc.y, vc.z, vc.w}};
        #pragma unroll
        for (int q = 0; q < 4; q++) {
            float a = 0.f;
            #pragma unroll
            for (int k = 0; k < HH; k++) a += ha[k] * w3T[(3 * CC + c + q) * HH + k];
            atomicAdd(avr + (CC + c + q) * 3 + 0, m1v[q][0] * a);
            atomicAdd(avr + (CC + c + q) * 3 + 1, m1v[q][1] * a);
            atomicAdd(avr + (CC + c + q) * 3 + 2, m1v[q][2] * a);
        }
    }
}

// ---------------- node output ----------------
__global__ __launch_bounds__(256) void k_node_out(
    const float* __restrict__ agg_s, const float* __restrict__ agg_v,
    const float* __restrict__ xs, const float* __restrict__ xv,
    const float* __restrict__ W20, const float* __restrict__ W21,
    const float* __restrict__ Wsk0, const float* __restrict__ Wsk1,
    const int* __restrict__ species,
    float* __restrict__ out, int N) {
    const int tid = threadIdx.x;
    const int n0 = blockIdx.x * 4;

    __shared__ float as_l[4 * 256];
    __shared__ float av_l[4 * 768];
    __shared__ float xs_l[4 * 128];
    __shared__ float xv_l[4 * 384];
    __shared__ float s_l[4 * 256];

    for (int i = tid; i < 4 * 256; i += 256) as_l[i] = agg_s[(size_t)n0 * 256 + i];
    for (int i = tid; i < 4 * 768; i += 256) av_l[i] = agg_v[(size_t)n0 * 768 + i];
    for (int i = tid; i < 4 * 128; i += 256) xs_l[i] = xs[(size_t)n0 * 128 + i];
    for (int i = tid; i < 4 * 384; i += 256) xv_l[i] = xv[(size_t)n0 * 384 + i];
    int sp[4];
    #pragma unroll
    for (int n = 0; n < 4; n++) sp[n] = species[n0 + n];
    __syncthreads();

    const float k_mat = 0.17677669529663687f * 0.0625f; // inv_nb * inv_2c
    const float inv_c = 0.08838834764831845f;

    // phase A: s (2C per node), thread = output channel d
    {
        const int d = tid;
        float am[4] = {0.f, 0.f, 0.f, 0.f};
        for (int c = 0; c < 256; c++) {
            float w = W20[c * 256 + d];
            #pragma unroll
            for (int n = 0; n < 4; n++) am[n] += as_l[n * 256 + c] * w;
        }
        float ak[4] = {0.f, 0.f, 0.f, 0.f};
        for (int c = 0; c < 128; c++) {
            #pragma unroll
            for (int n = 0; n < 4; n++) {
                float w = Wsk0[((size_t)sp[n] * 128 + c) * 256 + d];
                ak[n] += xs_l[n * 128 + c] * w;
            }
        }
        #pragma unroll
        for (int n = 0; n < 4; n++) s_l[n * 256 + d] = am[n] * k_mat + ak[n] * inv_c;
    }
    __syncthreads();

    // out_s = silu(s[:C])
    if (tid < 128) {
        #pragma unroll
        for (int n = 0; n < 4; n++)
            out[(size_t)(n0 + n) * 512 + tid] = silu_f(s_l[n * 256 + tid]);
    }

    // phase B: v (C x 3 per node), threads split: d = tid&127, half = tid>>7
    {
        const int d = tid & 127;
        const int half = tid >> 7;
        int spB[2];
        #pragma unroll
        for (int nn = 0; nn < 2; nn++) spB[nn] = species[n0 + half * 2 + nn];

        float am[2][3] = {};
        for (int c = 0; c < 256; c++) {
            float w = W21[c * 128 + d];
            #pragma unroll
            for (int nn = 0; nn < 2; nn++) {
                int n = half * 2 + nn;
                #pragma unroll
                for (int i = 0; i < 3; i++) am[nn][i] += av_l[n * 768 + c * 3 + i] * w;
            }
        }
        float ak[2][3] = {};
        for (int c = 0; c < 128; c++) {
            #pragma unroll
            for (int nn = 0; nn < 2; nn++) {
                int n = half * 2 + nn;
                float w = Wsk1[((size_t)spB[nn] * 128 + c) * 128 + d];
                #pragma unroll
                for (int i = 0; i < 3; i++) ak[nn][i] += xv_l[n * 384 + c * 3 + i] * w;
            }
        }
        #pragma unroll
        for (int nn = 0; nn < 2; nn++) {
            int n = half * 2 + nn;
            float g = silu_f(s_l[n * 256 + 128 + d]);
            #pragma unroll
            for (int i = 0; i < 3; i++)
                out[(size_t)(n0 + n) * 512 + 128 + d * 3 + i] =
                    (am[nn][i] * k_mat + ak[nn][i] * inv_c) * g;
        }
    }
}

extern "C" void kernel_launch(void* const* d_in, const int* in_sizes, int n_in,
                              void* d_out, int out_size, void* d_ws, size_t ws_size,
                              hipStream_t stream) {
    const float* xs   = (const float*)d_in[0];
    const float* xv   = (const float*)d_in[1];
    const float* evec = (const float*)d_in[2];
    const float* rb   = (const float*)d_in[3];
    const float* W10  = (const float*)d_in[4];
    const float* W11  = (const float*)d_in[5];
    const float* w0   = (const float*)d_in[6];
    const float* w1   = (const float*)d_in[7];
    const float* w2   = (const float*)d_in[8];
    const float* w3   = (const float*)d_in[9];
    const float* W20  = (const float*)d_in[10];
    const float* W21  = (const float*)d_in[11];
    const float* Wsk0 = (const float*)d_in[12];
    const float* Wsk1 = (const float*)d_in[13];
    const int* species = (const int*)d_in[14];
    const int* snd = (const int*)d_in[15];
    const int* rcv = (const int*)d_in[16];

    const int N = in_sizes[0] / CC;   // 4000
    const int E = in_sizes[2] / 3;    // 128000

    float* ws   = (float*)d_ws;
    float* y0   = ws;
    float* y1   = y0 + (size_t)N * CC;
    float* aggs = y1 + (size_t)N * CC * 3;
    float* aggv = aggs + (size_t)N * 2 * CC;
    float* w0T  = aggv + (size_t)N * 2 * CC * 3;
    float* w1T  = w0T + 64 * 8;
    float* w2T  = w1T + 64 * 64;
    float* w3T  = w2T + 64 * 64;

    int zeroN = N * 2 * CC + N * 2 * CC * 3;
    hipLaunchKernelGGL(k_zero, dim3(1024), dim3(256), 0, stream, aggs, zeroN);
    hipLaunchKernelGGL(k_prep, dim3(128), dim3(256), 0, stream,
                       w0, w1, w2, w3, w0T, w1T, w2T, w3T);
    hipLaunchKernelGGL(k_node_lin, dim3(N / 4), dim3(128), 0, stream,
                       xs, xv, W10, W11, y0, y1, N);
    hipLaunchKernelGGL(k_edge, dim3((E + 255) / 256), dim3(256), 0, stream,
                       rb, evec, snd, rcv, y0, y1, w0T, w1T, w2T, w3T, aggs, aggv, E);
    hipLaunchKernelGGL(k_node_out, dim3(N / 4), dim3(256), 0, stream,
                       aggs, aggv, xs, xv, W20, W21, Wsk0, Wsk1, species,
                       (float*)d_out, N);
}

// Round 2
// 609.498 us; speedup vs baseline: 11.6637x; 11.6637x over previous
//
#include <hip/hip_runtime.h>
#include <math.h>

#define CC 128
#define HH 64
#define RBD 8

__device__ __forceinline__ float silu_f(float x) {
    return x / (1.0f + __expf(-x));
}

// ---------------- transpose MLP weights ----------------
__global__ void k_prep(const float* __restrict__ w0, const float* __restrict__ w1,
                       const float* __restrict__ w2, const float* __restrict__ w3,
                       float* __restrict__ w0T, float* __restrict__ w1T,
                       float* __restrict__ w2T, float* __restrict__ w3T) {
    int i = blockIdx.x * blockDim.x + threadIdx.x;
    if (i < 64 * 8) { int m = i / 8, k = i % 8; w0T[i] = w0[k * 64 + m]; }
    if (i < 64 * 64) { int m = i / 64, k = i % 64; w1T[i] = w1[k * 64 + m]; w2T[i] = w2[k * 64 + m]; }
    if (i < 512 * 64) { int j = i / 64, k = i % 64; w3T[i] = w3[k * 512 + j]; }
}

// ---------------- CSR build ----------------
__global__ void k_hist(const int* __restrict__ rcv, int* __restrict__ deg, int E_) {
    int e = blockIdx.x * blockDim.x + threadIdx.x;
    if (e < E_) atomicAdd(&deg[rcv[e]], 1);
}

__global__ __launch_bounds__(1024) void k_scan(const int* __restrict__ deg,
                                               int* __restrict__ off, int N) {
    __shared__ int s[1024];
    int t = threadIdx.x;
    int b = t * 4;
    int a0 = (b + 0 < N) ? deg[b + 0] : 0;
    int a1 = (b + 1 < N) ? deg[b + 1] : 0;
    int a2 = (b + 2 < N) ? deg[b + 2] : 0;
    int a3 = (b + 3 < N) ? deg[b + 3] : 0;
    int part = a0 + a1 + a2 + a3;
    s[t] = part;
    __syncthreads();
    for (int d = 1; d < 1024; d <<= 1) {
        int v = (t >= d) ? s[t - d] : 0;
        __syncthreads();
        s[t] += v;
        __syncthreads();
    }
    int excl = s[t] - part;
    if (b + 0 <= N) off[b + 0] = excl;
    if (b + 1 <= N) off[b + 1] = excl + a0;
    if (b + 2 <= N) off[b + 2] = excl + a0 + a1;
    if (b + 3 <= N) off[b + 3] = excl + a0 + a1 + a2;
}

__global__ void k_scatter(const int* __restrict__ rcv, const int* __restrict__ off,
                          int* __restrict__ cur, int* __restrict__ elist, int E_) {
    int e = blockIdx.x * blockDim.x + threadIdx.x;
    if (e < E_) {
        int r = rcv[e];
        int p = atomicAdd(&cur[r], 1);
        elist[off[r] + p] = e;
    }
}

// ---------------- node linear ----------------
__global__ __launch_bounds__(128) void k_node_lin(
    const float* __restrict__ xs, const float* __restrict__ xv,
    const float* __restrict__ W10, const float* __restrict__ W11,
    float* __restrict__ y0, float* __restrict__ y1, int N) {
    const int d = threadIdx.x;
    const int n0 = blockIdx.x * 4;
    const float inv_c = 0.08838834764831845f;
    float a0[4] = {0.f, 0.f, 0.f, 0.f};
    float av[4][3] = {};
    #pragma unroll 4
    for (int c = 0; c < CC; c++) {
        float w10 = W10[c * CC + d];
        float w11 = W11[c * CC + d];
        #pragma unroll
        for (int n = 0; n < 4; n++) {
            a0[n] += xs[(n0 + n) * CC + c] * w10;
            #pragma unroll
            for (int i = 0; i < 3; i++)
                av[n][i] += xv[((n0 + n) * CC + c) * 3 + i] * w11;
        }
    }
    #pragma unroll
    for (int n = 0; n < 4; n++) {
        y0[(n0 + n) * CC + d] = a0[n] * inv_c;
        #pragma unroll
        for (int i = 0; i < 3; i++)
            y1[((n0 + n) * CC + d) * 3 + i] = av[n][i] * inv_c;
    }
}

// ---------------- per-edge radial MLP -> h2 ----------------
__device__ __forceinline__ void layer64(const float4* a, float4* b,
                                        const float* __restrict__ W) {
    #pragma unroll
    for (int m = 0; m < 16; m++) {
        float s0 = 0.f, s1 = 0.f, s2 = 0.f, s3 = 0.f;
        const float* w0p = W + (4 * m + 0) * 64;
        const float* w1p = W + (4 * m + 1) * 64;
        const float* w2p = W + (4 * m + 2) * 64;
        const float* w3p = W + (4 * m + 3) * 64;
        #pragma unroll
        for (int k = 0; k < 16; k++) {
            float4 av = a[k];
            s0 += av.x * w0p[4 * k + 0] + av.y * w0p[4 * k + 1] + av.z * w0p[4 * k + 2] + av.w * w0p[4 * k + 3];
            s1 += av.x * w1p[4 * k + 0] + av.y * w1p[4 * k + 1] + av.z * w1p[4 * k + 2] + av.w * w1p[4 * k + 3];
            s2 += av.x * w2p[4 * k + 0] + av.y * w2p[4 * k + 1] + av.z * w2p[4 * k + 2] + av.w * w2p[4 * k + 3];
            s3 += av.x * w3p[4 * k + 0] + av.y * w3p[4 * k + 1] + av.z * w3p[4 * k + 2] + av.w * w3p[4 * k + 3];
        }
        b[m] = make_float4(silu_f(s0), silu_f(s1), silu_f(s2), silu_f(s3));
    }
}

__global__ void k_mlp(const float* __restrict__ rb,
                      const float* __restrict__ w0T, const float* __restrict__ w1T,
                      const float* __restrict__ w2T,
                      float* __restrict__ h2, int E_) {
    int e = blockIdx.x * blockDim.x + threadIdx.x;
    if (e >= E_) return;

    float rbv[RBD];
    #pragma unroll
    for (int k = 0; k < RBD; k++) rbv[k] = rb[e * RBD + k];

    float4 a[16], b[16];
    // layer 0: 8 -> 64
    #pragma unroll
    for (int m = 0; m < 16; m++) {
        float s0 = 0.f, s1 = 0.f, s2 = 0.f, s3 = 0.f;
        #pragma unroll
        for (int k = 0; k < RBD; k++) {
            float rv = rbv[k];
            s0 += rv * w0T[(4 * m + 0) * RBD + k];
            s1 += rv * w0T[(4 * m + 1) * RBD + k];
            s2 += rv * w0T[(4 * m + 2) * RBD + k];
            s3 += rv * w0T[(4 * m + 3) * RBD + k];
        }
        a[m] = make_float4(silu_f(s0), silu_f(s1), silu_f(s2), silu_f(s3));
    }
    layer64(a, b, w1T);   // layer 1
    layer64(b, a, w2T);   // layer 2 -> a holds h2
    float4* out = (float4*)(h2 + (size_t)e * HH);
    #pragma unroll
    for (int q = 0; q < 16; q++) out[q] = a[q];
}

// ---------------- CSR gather: block = node, thread = w3 output column ----------------
__global__ __launch_bounds__(512) void k_gather(
    const int* __restrict__ off, const int* __restrict__ elist,
    const int* __restrict__ snd, const float* __restrict__ evec,
    const float* __restrict__ h2, const float* __restrict__ w3T,
    const float* __restrict__ y0, const float* __restrict__ y1,
    float* __restrict__ agg_s, float* __restrict__ agg_v) {
    const int r = blockIdx.x;
    const int tid = threadIdx.x;
    const int part = tid >> 7;   // 0..3
    const int c = tid & 127;

    // this thread's w3 column in registers
    float wreg[64];
    {
        const float* wp = w3T + (size_t)tid * 64;
        #pragma unroll
        for (int k = 0; k < 64; k++) wreg[k] = wp[k];
    }

    const int start = off[r];
    const int end = off[r + 1];

    float acc0 = 0.f, acc1 = 0.f, acc2 = 0.f;
    const float SQ3 = 1.7320508075688772f;

    for (int j = start; j < end; j++) {
        int e = elist[j];
        e = __builtin_amdgcn_readfirstlane(e);
        int s = snd[e];
        s = __builtin_amdgcn_readfirstlane(s);

        float e0 = evec[(size_t)e * 3 + 0];
        float e1 = evec[(size_t)e * 3 + 1];
        float e2 = evec[(size_t)e * 3 + 2];
        float rn = sqrtf(e0 * e0 + e1 * e1 + e2 * e2);
        float inv = 1.0f / fmaxf(rn, 1e-12f);
        float ux = e0 * inv, uy = e1 * inv, uz = e2 * inv;

        // dot(h2[e], wreg) — h2 loads are wave-uniform (broadcast)
        const float* __restrict__ h2e = h2 + ((size_t)e << 6);
        float ws0 = 0.f, ws1 = 0.f, ws2 = 0.f, ws3 = 0.f;
        #pragma unroll
        for (int k = 0; k < 16; k++) {
            ws0 += h2e[4 * k + 0] * wreg[4 * k + 0];
            ws1 += h2e[4 * k + 1] * wreg[4 * k + 1];
            ws2 += h2e[4 * k + 2] * wreg[4 * k + 2];
            ws3 += h2e[4 * k + 3] * wreg[4 * k + 3];
        }
        float wsum = (ws0 + ws1) + (ws2 + ws3);

        if (part == 0) {
            float f = y0[(size_t)s * CC + c];
            acc0 += f * wsum;
        } else if (part == 1) {
            const float* yp = y1 + ((size_t)s * CC + c) * 3;
            float f = yp[0] * ux + yp[1] * uy + yp[2] * uz;
            acc0 += f * wsum;
        } else if (part == 2) {
            float f = y0[(size_t)s * CC + c];
            float bb = f * wsum * SQ3;
            acc0 += bb * ux; acc1 += bb * uy; acc2 += bb * uz;
        } else {
            const float* yp = y1 + ((size_t)s * CC + c) * 3;
            acc0 += yp[0] * wsum; acc1 += yp[1] * wsum; acc2 += yp[2] * wsum;
        }
    }

    if (part == 0) {
        agg_s[(size_t)r * 2 * CC + c] = acc0;
    } else if (part == 1) {
        agg_s[(size_t)r * 2 * CC + CC + c] = acc0;
    } else if (part == 2) {
        float* o = agg_v + ((size_t)r * 2 * CC + c) * 3;
        o[0] = acc0; o[1] = acc1; o[2] = acc2;
    } else {
        float* o = agg_v + ((size_t)r * 2 * CC + CC + c) * 3;
        o[0] = acc0; o[1] = acc1; o[2] = acc2;
    }
}

// ---------------- node output ----------------
__global__ __launch_bounds__(256) void k_node_out(
    const float* __restrict__ agg_s, const float* __restrict__ agg_v,
    const float* __restrict__ xs, const float* __restrict__ xv,
    const float* __restrict__ W20, const float* __restrict__ W21,
    const float* __restrict__ Wsk0, const float* __restrict__ Wsk1,
    const int* __restrict__ species,
    float* __restrict__ out, int N) {
    const int tid = threadIdx.x;
    const int n0 = blockIdx.x * 4;

    __shared__ float as_l[4 * 256];
    __shared__ float av_l[4 * 768];
    __shared__ float xs_l[4 * 128];
    __shared__ float xv_l[4 * 384];
    __shared__ float s_l[4 * 256];

    for (int i = tid; i < 4 * 256; i += 256) as_l[i] = agg_s[(size_t)n0 * 256 + i];
    for (int i = tid; i < 4 * 768; i += 256) av_l[i] = agg_v[(size_t)n0 * 768 + i];
    for (int i = tid; i < 4 * 128; i += 256) xs_l[i] = xs[(size_t)n0 * 128 + i];
    for (int i = tid; i < 4 * 384; i += 256) xv_l[i] = xv[(size_t)n0 * 384 + i];
    int sp[4];
    #pragma unroll
    for (int n = 0; n < 4; n++) sp[n] = species[n0 + n];
    __syncthreads();

    const float k_mat = 0.17677669529663687f * 0.0625f; // inv_nb * inv_2c
    const float inv_c = 0.08838834764831845f;

    {
        const int d = tid;
        float am[4] = {0.f, 0.f, 0.f, 0.f};
        for (int cc = 0; cc < 256; cc++) {
            float w = W20[cc * 256 + d];
            #pragma unroll
            for (int n = 0; n < 4; n++) am[n] += as_l[n * 256 + cc] * w;
        }
        float ak[4] = {0.f, 0.f, 0.f, 0.f};
        for (int cc = 0; cc < 128; cc++) {
            #pragma unroll
            for (int n = 0; n < 4; n++) {
                float w = Wsk0[((size_t)sp[n] * 128 + cc) * 256 + d];
                ak[n] += xs_l[n * 128 + cc] * w;
            }
        }
        #pragma unroll
        for (int n = 0; n < 4; n++) s_l[n * 256 + d] = am[n] * k_mat + ak[n] * inv_c;
    }
    __syncthreads();

    if (tid < 128) {
        #pragma unroll
        for (int n = 0; n < 4; n++)
            out[(size_t)(n0 + n) * 512 + tid] = silu_f(s_l[n * 256 + tid]);
    }

    {
        const int d = tid & 127;
        const int half = tid >> 7;
        int spB[2];
        #pragma unroll
        for (int nn = 0; nn < 2; nn++) spB[nn] = species[n0 + half * 2 + nn];

        float am[2][3] = {};
        for (int cc = 0; cc < 256; cc++) {
            float w = W21[cc * 128 + d];
            #pragma unroll
            for (int nn = 0; nn < 2; nn++) {
                int n = half * 2 + nn;
                #pragma unroll
                for (int i = 0; i < 3; i++) am[nn][i] += av_l[n * 768 + cc * 3 + i] * w;
            }
        }
        float ak[2][3] = {};
        for (int cc = 0; cc < 128; cc++) {
            #pragma unroll
            for (int nn = 0; nn < 2; nn++) {
                int n = half * 2 + nn;
                float w = Wsk1[((size_t)spB[nn] * 128 + cc) * 128 + d];
                #pragma unroll
                for (int i = 0; i < 3; i++) ak[nn][i] += xv_l[n * 384 + cc * 3 + i] * w;
            }
        }
        #pragma unroll
        for (int nn = 0; nn < 2; nn++) {
            int n = half * 2 + nn;
            float g = silu_f(s_l[n * 256 + 128 + d]);
            #pragma unroll
            for (int i = 0; i < 3; i++)
                out[(size_t)(n0 + n) * 512 + 128 + d * 3 + i] =
                    (am[nn][i] * k_mat + ak[nn][i] * inv_c) * g;
        }
    }
}

extern "C" void kernel_launch(void* const* d_in, const int* in_sizes, int n_in,
                              void* d_out, int out_size, void* d_ws, size_t ws_size,
                              hipStream_t stream) {
    const float* xs   = (const float*)d_in[0];
    const float* xv   = (const float*)d_in[1];
    const float* evec = (const float*)d_in[2];
    const float* rb   = (const float*)d_in[3];
    const float* W10  = (const float*)d_in[4];
    const float* W11  = (const float*)d_in[5];
    const float* w0   = (const float*)d_in[6];
    const float* w1   = (const float*)d_in[7];
    const float* w2   = (const float*)d_in[8];
    const float* w3   = (const float*)d_in[9];
    const float* W20  = (const float*)d_in[10];
    const float* W21  = (const float*)d_in[11];
    const float* Wsk0 = (const float*)d_in[12];
    const float* Wsk1 = (const float*)d_in[13];
    const int* species = (const int*)d_in[14];
    const int* snd = (const int*)d_in[15];
    const int* rcv = (const int*)d_in[16];

    const int N = in_sizes[0] / CC;   // 4000
    const int E = in_sizes[2] / 3;    // 128000

    float* ws   = (float*)d_ws;
    float* y0   = ws;
    float* y1   = y0 + (size_t)N * CC;
    float* aggs = y1 + (size_t)N * CC * 3;
    float* aggv = aggs + (size_t)N * 2 * CC;
    float* w0T  = aggv + (size_t)N * 2 * CC * 3;
    float* w1T  = w0T + 64 * 8;
    float* w2T  = w1T + 64 * 64;
    float* w3T  = w2T + 64 * 64;
    float* h2   = w3T + 512 * 64;
    int*   deg  = (int*)(h2 + (size_t)E * HH);
    int*   cur  = deg + 4096;
    int*   off  = cur + 4096;
    int*   elist = off + 4160;

    hipMemsetAsync(deg, 0, 2 * 4096 * sizeof(int), stream);
    hipLaunchKernelGGL(k_hist, dim3((E + 255) / 256), dim3(256), 0, stream, rcv, deg, E);
    hipLaunchKernelGGL(k_scan, dim3(1), dim3(1024), 0, stream, deg, off, N);
    hipLaunchKernelGGL(k_scatter, dim3((E + 255) / 256), dim3(256), 0, stream,
                       rcv, off, cur, elist, E);
    hipLaunchKernelGGL(k_prep, dim3(128), dim3(256), 0, stream,
                       w0, w1, w2, w3, w0T, w1T, w2T, w3T);
    hipLaunchKernelGGL(k_node_lin, dim3(N / 4), dim3(128), 0, stream,
                       xs, xv, W10, W11, y0, y1, N);
    hipLaunchKernelGGL(k_mlp, dim3((E + 255) / 256), dim3(256), 0, stream,
                       rb, w0T, w1T, w2T, h2, E);
    hipLaunchKernelGGL(k_gather, dim3(N), dim3(512), 0, stream,
                       off, elist, snd, evec, h2, w3T, y0, y1, aggs, aggv);
    hipLaunchKernelGGL(k_node_out, dim3(N / 4), dim3(256), 0, stream,
                       aggs, aggv, xs, xv, W20, W21, Wsk0, Wsk1, species,
                       (float*)d_out, N);
}